// Round 6
// baseline (880.509 us; speedup 1.0000x reference)
//
#include <hip/hip_runtime.h>
#include <hip/hip_bf16.h>
#include <math.h>

// Problem constants (pinned by reference)
constexpr int BB = 4;
constexpr int TT = 512;
constexpr int DD = 2048;
constexpr int HH = 6;
constexpr int KK = 256;   // head_k_dim
constexpr int VV = 512;   // head_v_dim
constexpr int NHOUSE = 2;
constexpr int MM = BB * TT;          // 2048 rows
constexpr int KEY_DIM = HH * KK;     // 1536
constexpr int VAL_DIM = HH * VV;     // 3072

// P (f16) row layout: q[0,1536) k[1536,4608) v[4608,10752) g[10752,13824)
constexpr int PST  = 13824;
constexpr int QOFF = 0;
constexpr int KOFF = 1536;
constexpr int VOFF = 4608;
constexpr int GOFF = 10752;

// ---- workspace layout (FLOAT units) ----
constexpr size_t SZ_P    = (size_t)MM * PST / 2;         // 14,155,776 (f16)
constexpr size_t SZ_WCAT = (size_t)PST * DD / 2;         // 14,155,776 (f16)
constexpr size_t SZ_X16  = (size_t)MM * DD / 2;          //  2,097,152 (f16)
constexpr size_t SZ_BG   = (size_t)(MM + 2) * HH * 4;    //     49,200
constexpr size_t SZ_OMID = (size_t)MM * VAL_DIM;         //  6,291,456
constexpr size_t SZ_O2   = (size_t)MM * VAL_DIM / 2;     //  1,572,864 (f16)
constexpr size_t SZ_WO16 = (size_t)DD * VAL_DIM / 2;     //  1,572,864 (f16)

constexpr size_t OFF_P    = 0;
constexpr size_t OFF_WCAT = OFF_P + SZ_P;
constexpr size_t OFF_X16  = OFF_WCAT + SZ_WCAT;
constexpr size_t OFF_BG   = OFF_X16 + SZ_X16;
constexpr size_t WS_PEAK  = OFF_BG + SZ_BG;              // 121.8 MB
static_assert(WS_PEAK <= 31494144, "stay under round-4-proven 126.0 MB");
// after proj GEMM: Wcat/x16 dead -> o_mid overlays Wcat
constexpr size_t OFF_OMID = OFF_WCAT;
// after recurrence: o2 + wo16 also inside the (larger) Wcat region
constexpr size_t OFF_O2   = OFF_WCAT + SZ_OMID;
constexpr size_t OFF_WO16 = OFF_O2 + SZ_O2;
static_assert(OFF_WO16 + SZ_WO16 <= OFF_WCAT + SZ_WCAT, "o_mid+o2+wo16 fit in Wcat");

__device__ __forceinline__ float rsqrt_nr(float x) {
  float r = rsqrtf(x);
  return r * (1.5f - 0.5f * x * r * r);
}
__device__ __forceinline__ float sigmoidf_(float x) {
  return 1.f / (1.f + expf(-x));
}
__device__ __forceinline__ short f2h(float f) {
  _Float16 h = (_Float16)f;
  short s;
  __builtin_memcpy(&s, &h, 2);
  return s;
}

typedef __attribute__((ext_vector_type(8))) _Float16 f16x8;
typedef __attribute__((ext_vector_type(4))) _Float16 f16x4;
typedef __attribute__((ext_vector_type(4))) float f32x4;

__device__ __forceinline__ void gload_lds16(const short* g, short* l) {
  __builtin_amdgcn_global_load_lds(
      (const __attribute__((address_space(1))) void*)g,
      (__attribute__((address_space(3))) void*)l, 16, 0, 0);
}

// ---------------------------------------------------------------------------
// fp32 -> fp16 flat conversion, 4 elems/thread.
// ---------------------------------------------------------------------------
__global__ __launch_bounds__(256) void cvt_f16(const float* __restrict__ src,
                                               short* __restrict__ dst, int n) {
  int i = (blockIdx.x * 256 + threadIdx.x) << 2;
  if (i >= n) return;
  float4 v = *(const float4*)(src + i);
  short4 r;
  r.x = f2h(v.x); r.y = f2h(v.y); r.z = f2h(v.z); r.w = f2h(v.w);
  *(short4*)(dst + i) = r;
}

// ---------------------------------------------------------------------------
// C = act(A * B^T). modes: 0 = f32 out, 4 = merged f16 out with per-column
// activation. m97-verified structure.
// ---------------------------------------------------------------------------
__global__ __launch_bounds__(256) void gemm_f16(const short* __restrict__ A,
                                                const short* __restrict__ B,
                                                void* __restrict__ Cout,
                                                int ldc, int Kd, int lda, int ldb,
                                                int mode) {
  __shared__ __align__(16) short lds[8192];
  const int tid = threadIdx.x;
  const int lane = tid & 63;
  const int w = tid >> 6;
  const int m0 = blockIdx.x * 128;
  const int n0 = blockIdx.y * 128;

  const int sr = w * 32 + (lane >> 2);
  const int sc = (lane & 3) << 3;
  const short* ga1 = A + (size_t)(m0 + sr) * lda + sc;
  const short* ga2 = ga1 + (size_t)16 * lda;
  const short* gb1 = B + (size_t)(n0 + sr) * ldb + sc;
  const short* gb2 = gb1 + (size_t)16 * ldb;
  short* la1 = &lds[(size_t)w * 1024];
  short* la2 = la1 + 512;
  short* lb1 = &lds[4096 + (size_t)w * 1024];
  short* lb2 = lb1 + 512;

  const int fr = lane & 15;
  const int kg = lane >> 4;
  const int wmB = (w & 1) * 64;
  const int wnB = (w >> 1) * 64;
  int aoff[4], boff[4];
#pragma unroll
  for (int i = 0; i < 4; ++i) {
    aoff[i] = (wmB + i * 16 + fr) * 32 + kg * 8;
    boff[i] = 4096 + (wnB + i * 16 + fr) * 32 + kg * 8;
  }

  f32x4 acc[4][4];
#pragma unroll
  for (int i = 0; i < 4; ++i)
#pragma unroll
    for (int j = 0; j < 4; ++j) acc[i][j] = (f32x4){0.f, 0.f, 0.f, 0.f};

  const int nk = Kd >> 5;
  for (int kt = 0; kt < nk; ++kt) {
    const int ko = kt << 5;
    __syncthreads();
    gload_lds16(ga1 + ko, la1);
    gload_lds16(ga2 + ko, la2);
    gload_lds16(gb1 + ko, lb1);
    gload_lds16(gb2 + ko, lb2);
    __syncthreads();
    f16x8 af[4], bf[4];
#pragma unroll
    for (int i = 0; i < 4; ++i) af[i] = *(const f16x8*)(lds + aoff[i]);
#pragma unroll
    for (int j = 0; j < 4; ++j) bf[j] = *(const f16x8*)(lds + boff[j]);
#pragma unroll
    for (int i = 0; i < 4; ++i)
#pragma unroll
      for (int j = 0; j < 4; ++j)
        acc[i][j] = __builtin_amdgcn_mfma_f32_16x16x32_f16(af[i], bf[j], acc[i][j], 0, 0, 0);
  }

#pragma unroll
  for (int i = 0; i < 4; ++i) {
    const int row = m0 + wmB + i * 16 + kg * 4;
#pragma unroll
    for (int j = 0; j < 4; ++j) {
      const int col = n0 + wnB + j * 16 + fr;
#pragma unroll
      for (int e = 0; e < 4; ++e) {
        float v = acc[i][j][e];
        if (mode == 4) {
          if (col < GOFF) v = v / (1.f + expf(-v));  // silu (q/k/v)
          if (col < KOFF) v *= 0.0625f;              // q: K^-0.5 folded
          ((_Float16*)Cout)[(size_t)(row + e) * ldc + col] = (_Float16)v;
        } else {
          ((float*)Cout)[(size_t)(row + e) * ldc + col] = v;
        }
      }
    }
  }
}

// ---------------------------------------------------------------------------
// In-place L2-normalization of each f16 k head-row (256 halves) in P.
// ---------------------------------------------------------------------------
__global__ __launch_bounds__(256) void prep_kn(_Float16* __restrict__ P) {
  const int row = blockIdx.x * 4 + (threadIdx.x >> 6);
  const int lane = threadIdx.x & 63;
  const int m = row / (NHOUSE * HH);
  const int rem = row % (NHOUSE * HH);
  const int j = rem / HH;
  const int hh = rem % HH;
  _Float16* p = P + (size_t)m * PST + KOFF + j * KEY_DIM + hh * KK + lane * 4;
  f16x4 v = *(f16x4*)p;
  float f0 = (float)v[0], f1 = (float)v[1], f2 = (float)v[2], f3 = (float)v[3];
  float ss = f0 * f0 + f1 * f1 + f2 * f2 + f3 * f3;
#pragma unroll
  for (int off = 32; off; off >>= 1) ss += __shfl_xor(ss, off);
  float inv = rsqrt_nr(fmaxf(ss, 1e-24f));
  v[0] = (_Float16)(f0 * inv); v[1] = (_Float16)(f1 * inv);
  v[2] = (_Float16)(f2 * inv); v[3] = (_Float16)(f3 * inv);
  *(f16x4*)p = v;
}

// ---------------------------------------------------------------------------
// Small projections: packed float4 per (m,h): {beta0, beta1, exp(g), g}.
// ---------------------------------------------------------------------------
__global__ __launch_bounds__(256) void small_proj(const float* __restrict__ x,
                                                  const float* __restrict__ Wb,
                                                  const float* __restrict__ Wa,
                                                  const float* __restrict__ A_log,
                                                  const float* __restrict__ dt_bias,
                                                  float* __restrict__ bg) {
  const int m = blockIdx.x;
  const int tid = threadIdx.x;
  const int lane = tid & 63;
  const int wv = tid >> 6;
  __shared__ float xs[DD];
  __shared__ float ybuf[18];
#pragma unroll
  for (int i = 0; i < DD / 256; ++i) xs[tid + 256 * i] = x[(size_t)m * DD + tid + 256 * i];
  __syncthreads();
  for (int n = wv; n < 18; n += 4) {
    const float* wrow = (n < 12) ? (Wb + (size_t)n * DD) : (Wa + (size_t)(n - 12) * DD);
    float p = 0.f;
#pragma unroll
    for (int i = 0; i < DD / 64; ++i) p = fmaf(xs[lane + 64 * i], wrow[lane + 64 * i], p);
#pragma unroll
    for (int off = 32; off; off >>= 1) p += __shfl_xor(p, off);
    if (lane == 0) ybuf[n] = p;
  }
  __syncthreads();
  if (tid < 12) {
    const int j = tid / HH, hh = tid % HH;
    bg[((size_t)m * HH + hh) * 4 + j] = 2.f * sigmoidf_(ybuf[tid]);
  } else if (tid < 18) {
    const int hh = tid - 12;
    float z = ybuf[tid] + dt_bias[hh];
    float sp = fmaxf(z, 0.f) + log1pf(expf(-fabsf(z)));
    float g = -expf(A_log[hh]) * sp;
    bg[((size_t)m * HH + hh) * 4 + 2] = expf(g);
    bg[((size_t)m * HH + hh) * 4 + 3] = g;
  }
}

// ---------------------------------------------------------------------------
// Chunked gated delta-rule recurrence on MFMA (WY representation), v2.2:
// identical math/structure to round-4 (refcheck-verified), ONE change:
// __attribute__((amdgpu_waves_per_eu(2, 2))). Round-5 showed that
// __launch_bounds__'s 2nd arg is only a floor constraint -- the allocator
// still targeted 4 waves/EU (128 VGPR) and spilled the prefetch registers
// (rG[6]/rV/rbq, live across the whole loop) to scratch: WRITE 24.6->71 MB,
// FETCH 87->349 MB. LDS (157 KB -> 1 block/CU) pins real occupancy at
// 2 waves/EU regardless; min=max=2 forces the 256-VGPR budget so the
// prefetch set stays in registers.
// ---------------------------------------------------------------------------
constexpr int GP  = 264;  // G pitch (halves): [96][264]
constexpr int HTP = 264;  // hT pitch: [64][264]
constexpr int KTP = 72;   // KT pitch: [256][72]
constexpr int UP  = 68;   // U pitch (floats): [64][68]
constexpr int UTP = 72;   // UT pitch (halves): [64][72]
constexpr int WFP = 72;   // Wf16 pitch: [64][72]
constexpr int PMP = 72;   // Pm pitch: [32][72]
constexpr int VSP = 72;   // V-stage pitch: [64][72]
// byte offsets into smem
constexpr int OSM_G  = 0;       // 96*264*2 = 50688 (overlay region below)
constexpr int OSM_WF = 0;       //   64*72*2 = 9216
constexpr int OSM_WD = 9216;    //   4*16*17*4 = 4352
constexpr int OSM_PM = 13568;   //   32*72*2 = 4608  (-> 18176 <= 50688)
constexpr int OSM_VS = 50688;   // 64*72*2 = 9216
constexpr int OSM_HT = 59904;   // 64*264*2 = 33792
constexpr int OSM_KT = 93696;   // 256*72*2 = 36864
constexpr int OSM_U  = 130560;  // 64*68*4 = 17408
constexpr int OSM_UT = 147968;  // 64*72*2 = 9216
constexpr int OSM_SC = 157184;  // scalars: A[64], beta[64]
constexpr int SMEM_TOT = 157696;
static_assert(SMEM_TOT <= 163840, "LDS limit");

__global__ __launch_bounds__(512)
__attribute__((amdgpu_waves_per_eu(2, 2)))
void recurrence(const _Float16* __restrict__ P,
                const float4* __restrict__ bg,
                float* __restrict__ o) {
  constexpr int NVT = VV / 64;  // 8 v-tiles
  const int bid = blockIdx.x;
  const int b   = bid / (HH * NVT);
  const int rem = bid % (HH * NVT);
  const int hh  = rem / NVT;
  const int v0  = (rem % NVT) * 64;
  const int tid = threadIdx.x;
  const int lane = tid & 63;
  const int w = tid >> 6;        // 0..7
  const int cw = w & 3;          // col-tile
  const int rw = w >> 2;         // row-group
  const int fr = lane & 15;
  const int kg = lane >> 4;
  const int cc = 16 * cw + fr;   // this thread's output column (c or sigma)
  const int rtA = rw ? 2 : 0;    // first S/U row-tile
  const int rtQ = rw ? 5 : 4;    // Q row-tile (kept in regs)

  __shared__ __align__(16) char smem[SMEM_TOT];
  _Float16* Gp  = (_Float16*)(smem + OSM_G);
  _Float16* WFp = (_Float16*)(smem + OSM_WF);
  float*    WDp = (float*)(smem + OSM_WD);
  _Float16* PMp = (_Float16*)(smem + OSM_PM);
  _Float16* VSp = (_Float16*)(smem + OSM_VS);
  _Float16* HTp = (_Float16*)(smem + OSM_HT);
  _Float16* KTp = (_Float16*)(smem + OSM_KT);
  float*    Up  = (float*)(smem + OSM_U);
  _Float16* UTp = (_Float16*)(smem + OSM_UT);
  float*    SAp = (float*)(smem + OSM_SC);
  float*    SBp = SAp + 64;

  // fp32 state slice: hT[c][k], c = 16rt+kg*4+e (all 64), k = 32w+16ct+fr
  f32x4 hacc[4][2];
#pragma unroll
  for (int i = 0; i < 4; ++i)
#pragma unroll
    for (int j = 0; j < 2; ++j) hacc[i][j] = (f32x4){0.f, 0.f, 0.f, 0.f};
  // zero f16 state copy
  for (int i = tid; i < 33792 / 4; i += 512) ((int*)(smem + OSM_HT))[i] = 0;

  // ---- register prefetch machinery ----
  f16x8 rG[6], rV;
  float4 rbq;
  auto fetch_regs = [&](int t0n) {
    const _Float16* Pb1 = P + (size_t)(b * TT + t0n) * PST;
#pragma unroll
    for (int i = 0; i < 6; ++i) {
      const int idx = tid + 512 * i;        // 0..3071
      const int r = idx >> 5;
      const int c0 = (idx & 31) << 3;
      const _Float16* src = (r < 64)
          ? Pb1 + (size_t)(r >> 1) * PST + KOFF + (r & 1) * KEY_DIM + hh * KK + c0
          : Pb1 + (size_t)(r - 64) * PST + QOFF + hh * KK + c0;
      rG[i] = *(const f16x8*)src;
    }
    const int mv = tid >> 3, cv = (tid & 7) << 3;
    rV = *(const f16x8*)(Pb1 + (size_t)(mv >> 1) * PST + VOFF +
                         (mv & 1) * VAL_DIM + hh * VV + v0 + cv);
    rbq = bg[(size_t)(b * TT + t0n + (lane >> 1)) * HH + hh];
  };

  fetch_regs(0);  // prologue: chunk 0

#pragma unroll 1
  for (int g = 0; g < TT / 32; ++g) {
    const int t0 = g * 32;
    const int sbase = b * TT + t0;

    // ---- Phase A: regs -> LDS (G, VS), zero UT ----
#pragma unroll
    for (int i = 0; i < 6; ++i) {
      const int idx = tid + 512 * i;
      *(f16x8*)&Gp[(idx >> 5) * GP + ((idx & 31) << 3)] = rG[i];
    }
    *(f16x8*)&VSp[(tid >> 3) * VSP + ((tid & 7) << 3)] = rV;
    const float4 bq = rbq;
#pragma unroll
    for (int i = tid; i < 9216 / 4; i += 512) ((int*)(smem + OSM_UT))[i] = 0;
    __syncthreads();

    // ---- Phase B: decay scan (per-wave redundant) + scaled K transpose ----
    float ps = (lane & 1) ? 0.f : bq.w;  // ln(gamma) at even eff-steps
#pragma unroll
    for (int off = 1; off < 64; off <<= 1) {
      float nv = __shfl_up(ps, off);
      if (lane >= off) ps += nv;
    }
    const float tot = __shfl(ps, 63);
    const float Asv = expf(ps);          // A_s (inclusive)
    const float rv2 = expf(tot - ps);    // A63/A_s <= 1
    const float A63r = expf(tot);
    if (w == 0) { SAp[lane] = Asv; SBp[lane] = (lane & 1) ? bq.y : bq.x; }

    // KT[k][s] = (A63/A_s) * Keff[s][k], 4x4 in-reg transpose tiles
    {
      const int ts0 = (tid & 15) * 4;
      const int tk0 = ((tid >> 4) & 31) * 4;
      const float r0 = __shfl(rv2, ts0), r1 = __shfl(rv2, ts0 + 1);
      const float r2 = __shfl(rv2, ts0 + 2), r3 = __shfl(rv2, ts0 + 3);
      const _Float16 rh0 = (_Float16)r0, rh1 = (_Float16)r1;
      const _Float16 rh2 = (_Float16)r2, rh3 = (_Float16)r3;
#pragma unroll
      for (int it = 0; it < 2; ++it) {
        const int k0 = tk0 + 128 * it;
        f16x4 in0 = *(const f16x4*)&Gp[(ts0 + 0) * GP + k0];
        f16x4 in1 = *(const f16x4*)&Gp[(ts0 + 1) * GP + k0];
        f16x4 in2 = *(const f16x4*)&Gp[(ts0 + 2) * GP + k0];
        f16x4 in3 = *(const f16x4*)&Gp[(ts0 + 3) * GP + k0];
#pragma unroll
        for (int j = 0; j < 4; ++j) {
          f16x4 ov;
          ov[0] = in0[j] * rh0; ov[1] = in1[j] * rh1;
          ov[2] = in2[j] * rh2; ov[3] = in3[j] * rh3;
          *(f16x4*)&KTp[(k0 + j) * KTP + ts0] = ov;
        }
      }
    }

    // ---- issue next chunk's global loads (hidden under C..F) ----
    {
      const int gn = (g < TT / 32 - 1) ? g + 1 : g;
      fetch_regs(gn * 32);
    }
    __syncthreads();

    // ---- Phase C: big MFMAs. wave does col-tile cw, row-tiles
    //      {rtA, rtA+1, rtQ}. ph = rows @ hT^T, sq = rows @ Keff^T. ----
    f32x4 ph[3], sq[3];
#pragma unroll
    for (int j = 0; j < 3; ++j) { ph[j] = (f32x4){0.f,0.f,0.f,0.f}; sq[j] = (f32x4){0.f,0.f,0.f,0.f}; }
#pragma unroll
    for (int ks = 0; ks < 8; ++ks) {
      const int ko = ks * 32 + kg * 8;
      const f16x8 bf2 = *(const f16x8*)&HTp[cc * HTP + ko];  // hT col-tile
      const f16x8 bf1 = *(const f16x8*)&Gp[cc * GP + ko];    // Keff col-tile
#pragma unroll
      for (int j = 0; j < 3; ++j) {
        const int rt = (j < 2) ? (rtA + j) : rtQ;
        const f16x8 af = *(const f16x8*)&Gp[(16 * rt + fr) * GP + ko];
        ph[j] = __builtin_amdgcn_mfma_f32_16x16x32_f16(af, bf2, ph[j], 0, 0, 0);
        sq[j] = __builtin_amdgcn_mfma_f32_16x16x32_f16(af, bf1, sq[j], 0, 0, 0);
      }
    }
    // epilogue 1: b -> U (this wave's two row-tiles); Qh0 = ph[2] stays in regs
#pragma unroll
    for (int j = 0; j < 2; ++j) {
      const int rt = rtA + j;
#pragma unroll
      for (int e = 0; e < 4; ++e) {
        const int m = 16 * rt + kg * 4 + e;
        const float vv = (float)VSp[m * VSP + cc];
        Up[m * UP + cc] = SBp[m] * (vv - SAp[m] * ph[j][e]);
      }
    }
    __syncthreads();
    // epilogue 2: W (diag-zeroed f16 + fp32 diag blocks) and Pm, into G overlay
    {
      const float invAsig = 1.f / SAp[cc];
#pragma unroll
      for (int j = 0; j < 2; ++j) {
        const int rt = rtA + j;
#pragma unroll
        for (int e = 0; e < 4; ++e) {
          const int m = 16 * rt + kg * 4 + e;
          const float wv = SBp[m] * (SAp[m] * invAsig) * sq[j][e];
          if ((m >> 4) == cw) {
            WDp[cw * 272 + (m & 15) * 17 + (cc & 15)] = (cc < m) ? wv : 0.f;
            WFp[m * WFP + cc] = (_Float16)0.f;
          } else {
            WFp[m * WFP + cc] = (cc < m) ? (_Float16)wv : (_Float16)0.f;
          }
        }
      }
#pragma unroll
      for (int e = 0; e < 4; ++e) {
        const int tq = 16 * rw + kg * 4 + e;
        const int se = 2 * tq + 1;
        const float pv = (cc <= se) ? (SAp[se] * invAsig) * sq[2][e] : 0.f;
        PMp[tq * PMP + cc] = (_Float16)pv;
      }
    }
    __syncthreads();

    // ---- Phase D: blocked forward substitution (I+W)u = b ----
#pragma unroll 1
    for (int blk = 0; blk < 4; ++blk) {
      if (blk) {
        if (rw == 0) {
          f32x4 ta = (f32x4){0.f, 0.f, 0.f, 0.f};
#pragma unroll
          for (int ks = 0; ks < 2; ++ks) {
            const int ko = ks * 32 + kg * 8;
            const f16x8 af = *(const f16x8*)&WFp[(16 * blk + fr) * WFP + ko];
            const f16x8 bf = *(const f16x8*)&UTp[cc * UTP + ko];
            ta = __builtin_amdgcn_mfma_f32_16x16x32_f16(af, bf, ta, 0, 0, 0);
          }
#pragma unroll
          for (int e = 0; e < 4; ++e) {
            const int m = 16 * blk + kg * 4 + e;
            Up[m * UP + cc] -= ta[e];
          }
        }
        __syncthreads();
      }
      if (w == 0) {  // in-block 16x16 serial solve, lane = column (64 cols)
        float ub[16];
#pragma unroll
        for (int i = 0; i < 16; ++i) ub[i] = Up[(16 * blk + i) * UP + lane];
#pragma unroll
        for (int i = 1; i < 16; ++i)
#pragma unroll
          for (int j = 0; j < i; ++j)
            ub[i] -= WDp[blk * 272 + i * 17 + j] * ub[j];
#pragma unroll
        for (int i = 0; i < 16; ++i) Up[(16 * blk + i) * UP + lane] = ub[i];
        f16x8 p0, p1;
#pragma unroll
        for (int i = 0; i < 8; ++i) { p0[i] = (_Float16)ub[i]; p1[i] = (_Float16)ub[8 + i]; }
        *(f16x8*)&UTp[lane * UTP + 16 * blk]     = p0;
        *(f16x8*)&UTp[lane * UTP + 16 * blk + 8] = p1;
      }
      __syncthreads();
    }

    // ---- Phase E: outputs o = A*Qh0 + Pm @ U (rows 16rw..16rw+15) ----
    {
      f32x4 oa = (f32x4){0.f, 0.f, 0.f, 0.f};
#pragma unroll
      for (int ks = 0; ks < 2; ++ks) {
        const int ko = ks * 32 + kg * 8;
        const f16x8 bf = *(const f16x8*)&UTp[cc * UTP + ko];
        const f16x8 af = *(const f16x8*)&PMp[(16 * rw + fr) * PMP + ko];
        oa = __builtin_amdgcn_mfma_f32_16x16x32_f16(af, bf, oa, 0, 0, 0);
      }
      float* ob = o + ((size_t)sbase * HH + hh) * VV + v0 + cc;
#pragma unroll
      for (int e = 0; e < 4; ++e) {
        const int tq = 16 * rw + kg * 4 + e;
        ob[(size_t)tq * (HH * VV)] = oa[e] + SAp[2 * tq + 1] * ph[2][e];
      }
    }

    // ---- Phase F: state update h = A63*h + KT^T @ U (k-slice 32w..32w+31) ----
#pragma unroll
    for (int rt = 0; rt < 4; ++rt)
#pragma unroll
      for (int ct = 0; ct < 2; ++ct) hacc[rt][ct] *= A63r;
#pragma unroll
    for (int ks = 0; ks < 2; ++ks) {
      const int ko = ks * 32 + kg * 8;
      f16x8 af[4], bf[2];
#pragma unroll
      for (int rt = 0; rt < 4; ++rt) af[rt] = *(const f16x8*)&UTp[(16 * rt + fr) * UTP + ko];
#pragma unroll
      for (int ct = 0; ct < 2; ++ct) bf[ct] = *(const f16x8*)&KTp[(32 * w + 16 * ct + fr) * KTP + ko];
#pragma unroll
      for (int rt = 0; rt < 4; ++rt)
#pragma unroll
        for (int ct = 0; ct < 2; ++ct)
          hacc[rt][ct] = __builtin_amdgcn_mfma_f32_16x16x32_f16(af[rt], bf[ct], hacc[rt][ct], 0, 0, 0);
    }

    // ---- Phase G: refresh f16 state copy ----
#pragma unroll
    for (int rt = 0; rt < 4; ++rt)
#pragma unroll
      for (int ct = 0; ct < 2; ++ct)
#pragma unroll
        for (int e = 0; e < 4; ++e) {
          const int c = 16 * rt + kg * 4 + e;
          const int k = 32 * w + 16 * ct + fr;
          HTp[c * HTP + k] = (_Float16)hacc[rt][ct][e];
        }
    __syncthreads();
  }
}

// ---------------------------------------------------------------------------
// Gated RMSNorm. Reads o_mid fp32 + gate f16 (from P); writes o2 f16.
// ---------------------------------------------------------------------------
__global__ __launch_bounds__(256) void rms_gate_kernel(const float* __restrict__ o,
                                                       const _Float16* __restrict__ P,
                                                       const float* __restrict__ wn,
                                                       short* __restrict__ o2) {
  const int row = blockIdx.x;            // m*H + h
  const int m = row / HH;
  const int hh = row - m * HH;
  const int tid = threadIdx.x;
  const float* op = o + (size_t)row * VV;
  const _Float16* gp = P + (size_t)m * PST + GOFF + hh * VV;
  float a0 = op[tid], a1 = op[tid + 256];
  float ss = a0 * a0 + a1 * a1;
#pragma unroll
  for (int off = 32; off; off >>= 1) ss += __shfl_xor(ss, off);
  __shared__ float red[4];
  const int lane = tid & 63, wv = tid >> 6;
  if (lane == 0) red[wv] = ss;
  __syncthreads();
  float tot = red[0] + red[1] + red[2] + red[3];
  float inv = rsqrt_nr(tot * (1.f / (float)VV) + 1e-5f);
  float r0 = a0 * inv * wn[tid] * sigmoidf_((float)gp[tid]);
  float r1 = a1 * inv * wn[tid + 256] * sigmoidf_((float)gp[tid + 256]);
  _Float16* dst = (_Float16*)o2 + (size_t)m * VAL_DIM + hh * VV;
  dst[tid] = (_Float16)r0;
  dst[tid + 256] = (_Float16)r1;
}

// ---------------------------------------------------------------------------
extern "C" void kernel_launch(void* const* d_in, const int* in_sizes, int n_in,
                              void* d_out, int out_size, void* d_ws, size_t ws_size,
                              hipStream_t stream) {
  (void)in_sizes; (void)n_in; (void)out_size; (void)ws_size;
  const float* x       = (const float*)d_in[0];
  const float* Wq      = (const float*)d_in[1];
  const float* Wk      = (const float*)d_in[2];
  const float* Wv      = (const float*)d_in[3];
  const float* Wb      = (const float*)d_in[4];
  const float* Wa      = (const float*)d_in[5];
  const float* A_log   = (const float*)d_in[6];
  const float* dt_bias = (const float*)d_in[7];
  const float* Wg      = (const float*)d_in[8];
  const float* Wo      = (const float*)d_in[9];
  const float* onw     = (const float*)d_in[10];
  float* out = (float*)d_out;
  float* ws = (float*)d_ws;

  _Float16* P   = (_Float16*)(ws + OFF_P);
  short* wcat   = (short*)(ws + OFF_WCAT);
  short* x16    = (short*)(ws + OFF_X16);
  float* bgw    = ws + OFF_BG;
  float* o_mid  = ws + OFF_OMID;          // overlays Wcat after proj GEMM
  short* o2     = (short*)(ws + OFF_O2);
  short* wo16   = (short*)(ws + OFF_WO16);

  // 1. conversions: x + all projection weights into one concatenated buffer
  cvt_f16<<<4096, 256, 0, stream>>>(x, x16, MM * DD);
  small_proj<<<MM, 256, 0, stream>>>(x, Wb, Wa, A_log, dt_bias, bgw);
  cvt_f16<<<3072, 256, 0, stream>>>(Wq, wcat + (size_t)QOFF * DD, KEY_DIM * DD);
  cvt_f16<<<6144, 256, 0, stream>>>(Wk, wcat + (size_t)KOFF * DD, KEY_DIM * NHOUSE * DD);
  cvt_f16<<<12288, 256, 0, stream>>>(Wv, wcat + (size_t)VOFF * DD, VAL_DIM * NHOUSE * DD);
  cvt_f16<<<6144, 256, 0, stream>>>(Wg, wcat + (size_t)GOFF * DD, VAL_DIM * DD);

  // 2. ONE merged projection GEMM (f16 out, per-column activation), then
  //    in-place k normalization.
  gemm_f16<<<dim3(MM / 128, PST / 128), 256, 0, stream>>>(
      x16, wcat, (void*)P, PST, DD, DD, DD, 4);
  prep_kn<<<MM * NHOUSE * HH / 4, 256, 0, stream>>>(P);

  // 3. chunked MFMA recurrence (f16 operands, fp32 state), 8 waves/block
  recurrence<<<BB * HH * (VV / 64), 512, 0, stream>>>(P, (const float4*)bgw, o_mid);

  // 4. gated RMSNorm -> o2 f16 ; Wo -> f16
  rms_gate_kernel<<<MM * HH, 256, 0, stream>>>(o_mid, P, onw, o2);
  cvt_f16<<<6144, 256, 0, stream>>>(Wo, wo16, DD * VAL_DIM);

  // 5. output GEMM (f16 in, f32 out to d_out)
  gemm_f16<<<dim3(MM / 128, DD / 128), 256, 0, stream>>>(
      o2, wo16, out, DD, VAL_DIM, VAL_DIM, VAL_DIM, 0);
}

// Round 7
// 775.308 us; speedup vs baseline: 1.1357x; 1.1357x over previous
//
#include <hip/hip_runtime.h>
#include <hip/hip_bf16.h>
#include <math.h>

// Problem constants (pinned by reference)
constexpr int BB = 4;
constexpr int TT = 512;
constexpr int DD = 2048;
constexpr int HH = 6;
constexpr int KK = 256;   // head_k_dim
constexpr int VV = 512;   // head_v_dim
constexpr int NHOUSE = 2;
constexpr int MM = BB * TT;          // 2048 rows
constexpr int KEY_DIM = HH * KK;     // 1536
constexpr int VAL_DIM = HH * VV;     // 3072

// P (f16) row layout: q[0,1536) k[1536,4608) v[4608,10752) g[10752,13824)
constexpr int PST  = 13824;
constexpr int QOFF = 0;
constexpr int KOFF = 1536;
constexpr int VOFF = 4608;
constexpr int GOFF = 10752;

// ---- workspace layout (FLOAT units) ----
constexpr size_t SZ_P    = (size_t)MM * PST / 2;         // 14,155,776 (f16)
constexpr size_t SZ_WCAT = (size_t)PST * DD / 2;         // 14,155,776 (f16)
constexpr size_t SZ_X16  = (size_t)MM * DD / 2;          //  2,097,152 (f16)
constexpr size_t SZ_BG   = (size_t)(MM + 2) * HH * 4;    //     49,200
constexpr size_t SZ_OMID = (size_t)MM * VAL_DIM;         //  6,291,456
constexpr size_t SZ_O2   = (size_t)MM * VAL_DIM / 2;     //  1,572,864 (f16)
constexpr size_t SZ_WO16 = (size_t)DD * VAL_DIM / 2;     //  1,572,864 (f16)

constexpr size_t OFF_P    = 0;
constexpr size_t OFF_WCAT = OFF_P + SZ_P;
constexpr size_t OFF_X16  = OFF_WCAT + SZ_WCAT;
constexpr size_t OFF_BG   = OFF_X16 + SZ_X16;
constexpr size_t WS_PEAK  = OFF_BG + SZ_BG;              // 121.8 MB
static_assert(WS_PEAK <= 31494144, "stay under round-4-proven 126.0 MB");
// after proj GEMM: Wcat/x16 dead -> o_mid overlays Wcat
constexpr size_t OFF_OMID = OFF_WCAT;
// after recurrence: o2 + wo16 also inside the (larger) Wcat region
constexpr size_t OFF_O2   = OFF_WCAT + SZ_OMID;
constexpr size_t OFF_WO16 = OFF_O2 + SZ_O2;
static_assert(OFF_WO16 + SZ_WO16 <= OFF_WCAT + SZ_WCAT, "o_mid+o2+wo16 fit in Wcat");

__device__ __forceinline__ float rsqrt_nr(float x) {
  float r = rsqrtf(x);
  return r * (1.5f - 0.5f * x * r * r);
}
__device__ __forceinline__ float sigmoidf_(float x) {
  return 1.f / (1.f + expf(-x));
}
__device__ __forceinline__ short f2h(float f) {
  _Float16 h = (_Float16)f;
  short s;
  __builtin_memcpy(&s, &h, 2);
  return s;
}

typedef __attribute__((ext_vector_type(8))) _Float16 f16x8;
typedef __attribute__((ext_vector_type(4))) _Float16 f16x4;
typedef __attribute__((ext_vector_type(4))) float f32x4;

__device__ __forceinline__ void gload_lds16(const short* g, short* l) {
  __builtin_amdgcn_global_load_lds(
      (const __attribute__((address_space(1))) void*)g,
      (__attribute__((address_space(3))) void*)l, 16, 0, 0);
}

// ---------------------------------------------------------------------------
// fp32 -> fp16 flat conversion, 4 elems/thread.
// ---------------------------------------------------------------------------
__global__ __launch_bounds__(256) void cvt_f16(const float* __restrict__ src,
                                               short* __restrict__ dst, int n) {
  int i = (blockIdx.x * 256 + threadIdx.x) << 2;
  if (i >= n) return;
  float4 v = *(const float4*)(src + i);
  short4 r;
  r.x = f2h(v.x); r.y = f2h(v.y); r.z = f2h(v.z); r.w = f2h(v.w);
  *(short4*)(dst + i) = r;
}

// ---------------------------------------------------------------------------
// C = act(A * B^T). modes: 0 = f32 out, 4 = merged f16 out with per-column
// activation. m97-verified structure.
// ---------------------------------------------------------------------------
__global__ __launch_bounds__(256) void gemm_f16(const short* __restrict__ A,
                                                const short* __restrict__ B,
                                                void* __restrict__ Cout,
                                                int ldc, int Kd, int lda, int ldb,
                                                int mode) {
  __shared__ __align__(16) short lds[8192];
  const int tid = threadIdx.x;
  const int lane = tid & 63;
  const int w = tid >> 6;
  const int m0 = blockIdx.x * 128;
  const int n0 = blockIdx.y * 128;

  const int sr = w * 32 + (lane >> 2);
  const int sc = (lane & 3) << 3;
  const short* ga1 = A + (size_t)(m0 + sr) * lda + sc;
  const short* ga2 = ga1 + (size_t)16 * lda;
  const short* gb1 = B + (size_t)(n0 + sr) * ldb + sc;
  const short* gb2 = gb1 + (size_t)16 * ldb;
  short* la1 = &lds[(size_t)w * 1024];
  short* la2 = la1 + 512;
  short* lb1 = &lds[4096 + (size_t)w * 1024];
  short* lb2 = lb1 + 512;

  const int fr = lane & 15;
  const int kg = lane >> 4;
  const int wmB = (w & 1) * 64;
  const int wnB = (w >> 1) * 64;
  int aoff[4], boff[4];
#pragma unroll
  for (int i = 0; i < 4; ++i) {
    aoff[i] = (wmB + i * 16 + fr) * 32 + kg * 8;
    boff[i] = 4096 + (wnB + i * 16 + fr) * 32 + kg * 8;
  }

  f32x4 acc[4][4];
#pragma unroll
  for (int i = 0; i < 4; ++i)
#pragma unroll
    for (int j = 0; j < 4; ++j) acc[i][j] = (f32x4){0.f, 0.f, 0.f, 0.f};

  const int nk = Kd >> 5;
  for (int kt = 0; kt < nk; ++kt) {
    const int ko = kt << 5;
    __syncthreads();
    gload_lds16(ga1 + ko, la1);
    gload_lds16(ga2 + ko, la2);
    gload_lds16(gb1 + ko, lb1);
    gload_lds16(gb2 + ko, lb2);
    __syncthreads();
    f16x8 af[4], bf[4];
#pragma unroll
    for (int i = 0; i < 4; ++i) af[i] = *(const f16x8*)(lds + aoff[i]);
#pragma unroll
    for (int j = 0; j < 4; ++j) bf[j] = *(const f16x8*)(lds + boff[j]);
#pragma unroll
    for (int i = 0; i < 4; ++i)
#pragma unroll
      for (int j = 0; j < 4; ++j)
        acc[i][j] = __builtin_amdgcn_mfma_f32_16x16x32_f16(af[i], bf[j], acc[i][j], 0, 0, 0);
  }

#pragma unroll
  for (int i = 0; i < 4; ++i) {
    const int row = m0 + wmB + i * 16 + kg * 4;
#pragma unroll
    for (int j = 0; j < 4; ++j) {
      const int col = n0 + wnB + j * 16 + fr;
#pragma unroll
      for (int e = 0; e < 4; ++e) {
        float v = acc[i][j][e];
        if (mode == 4) {
          if (col < GOFF) v = v / (1.f + expf(-v));  // silu (q/k/v)
          if (col < KOFF) v *= 0.0625f;              // q: K^-0.5 folded
          ((_Float16*)Cout)[(size_t)(row + e) * ldc + col] = (_Float16)v;
        } else {
          ((float*)Cout)[(size_t)(row + e) * ldc + col] = v;
        }
      }
    }
  }
}

// ---------------------------------------------------------------------------
// In-place L2-normalization of each f16 k head-row (256 halves) in P.
// ---------------------------------------------------------------------------
__global__ __launch_bounds__(256) void prep_kn(_Float16* __restrict__ P) {
  const int row = blockIdx.x * 4 + (threadIdx.x >> 6);
  const int lane = threadIdx.x & 63;
  const int m = row / (NHOUSE * HH);
  const int rem = row % (NHOUSE * HH);
  const int j = rem / HH;
  const int hh = rem % HH;
  _Float16* p = P + (size_t)m * PST + KOFF + j * KEY_DIM + hh * KK + lane * 4;
  f16x4 v = *(f16x4*)p;
  float f0 = (float)v[0], f1 = (float)v[1], f2 = (float)v[2], f3 = (float)v[3];
  float ss = f0 * f0 + f1 * f1 + f2 * f2 + f3 * f3;
#pragma unroll
  for (int off = 32; off; off >>= 1) ss += __shfl_xor(ss, off);
  float inv = rsqrt_nr(fmaxf(ss, 1e-24f));
  v[0] = (_Float16)(f0 * inv); v[1] = (_Float16)(f1 * inv);
  v[2] = (_Float16)(f2 * inv); v[3] = (_Float16)(f3 * inv);
  *(f16x4*)p = v;
}

// ---------------------------------------------------------------------------
// Small projections: packed float4 per (m,h): {beta0, beta1, exp(g), g}.
// ---------------------------------------------------------------------------
__global__ __launch_bounds__(256) void small_proj(const float* __restrict__ x,
                                                  const float* __restrict__ Wb,
                                                  const float* __restrict__ Wa,
                                                  const float* __restrict__ A_log,
                                                  const float* __restrict__ dt_bias,
                                                  float* __restrict__ bg) {
  const int m = blockIdx.x;
  const int tid = threadIdx.x;
  const int lane = tid & 63;
  const int wv = tid >> 6;
  __shared__ float xs[DD];
  __shared__ float ybuf[18];
#pragma unroll
  for (int i = 0; i < DD / 256; ++i) xs[tid + 256 * i] = x[(size_t)m * DD + tid + 256 * i];
  __syncthreads();
  for (int n = wv; n < 18; n += 4) {
    const float* wrow = (n < 12) ? (Wb + (size_t)n * DD) : (Wa + (size_t)(n - 12) * DD);
    float p = 0.f;
#pragma unroll
    for (int i = 0; i < DD / 64; ++i) p = fmaf(xs[lane + 64 * i], wrow[lane + 64 * i], p);
#pragma unroll
    for (int off = 32; off; off >>= 1) p += __shfl_xor(p, off);
    if (lane == 0) ybuf[n] = p;
  }
  __syncthreads();
  if (tid < 12) {
    const int j = tid / HH, hh = tid % HH;
    bg[((size_t)m * HH + hh) * 4 + j] = 2.f * sigmoidf_(ybuf[tid]);
  } else if (tid < 18) {
    const int hh = tid - 12;
    float z = ybuf[tid] + dt_bias[hh];
    float sp = fmaxf(z, 0.f) + log1pf(expf(-fabsf(z)));
    float g = -expf(A_log[hh]) * sp;
    bg[((size_t)m * HH + hh) * 4 + 2] = expf(g);
    bg[((size_t)m * HH + hh) * 4 + 3] = g;
  }
}

// ---------------------------------------------------------------------------
// Chunked gated delta-rule recurrence on MFMA (WY representation), v2.3:
// identical math/phases to the round-3/4-verified version; the ONE change is
// staging: Phase A now loads global->reg->LDS with temps that DIE at the
// phase barrier (no cross-phase prefetch registers). Rounds 4-6 proved the
// allocator pins this 512-thread kernel at 128 VGPRs (neither
// __launch_bounds__ min-waves nor amdgpu_waves_per_eu moved it), so the
// long-lived rG[6]/rV/rbq prefetch set spilled to scratch: 430 MB/dispatch
// of scratch traffic = the whole 311->397us regression. Short-liveness
// staging fits in 128 VGPRs (Phase A ~105 live, Phase C ~80), costing only
// ~800 cyc exposed HBM latency per chunk (~5us total) -- and keeps the
// 8-wave / 2-waves-per-SIMD occupancy that was the point of v2.
// ---------------------------------------------------------------------------
constexpr int GP  = 264;  // G pitch (halves): [96][264]
constexpr int HTP = 264;  // hT pitch: [64][264]
constexpr int KTP = 72;   // KT pitch: [256][72]
constexpr int UP  = 68;   // U pitch (floats): [64][68]
constexpr int UTP = 72;   // UT pitch (halves): [64][72]
constexpr int WFP = 72;   // Wf16 pitch: [64][72]
constexpr int PMP = 72;   // Pm pitch: [32][72]
constexpr int VSP = 72;   // V-stage pitch: [64][72]
// byte offsets into smem
constexpr int OSM_G  = 0;       // 96*264*2 = 50688 (overlay region below)
constexpr int OSM_WF = 0;       //   64*72*2 = 9216
constexpr int OSM_WD = 9216;    //   4*16*17*4 = 4352
constexpr int OSM_PM = 13568;   //   32*72*2 = 4608  (-> 18176 <= 50688)
constexpr int OSM_VS = 50688;   // 64*72*2 = 9216
constexpr int OSM_HT = 59904;   // 64*264*2 = 33792
constexpr int OSM_KT = 93696;   // 256*72*2 = 36864
constexpr int OSM_U  = 130560;  // 64*68*4 = 17408
constexpr int OSM_UT = 147968;  // 64*72*2 = 9216
constexpr int OSM_SC = 157184;  // scalars: A[64], beta[64]
constexpr int SMEM_TOT = 157696;
static_assert(SMEM_TOT <= 163840, "LDS limit");

__global__ __launch_bounds__(512)
void recurrence(const _Float16* __restrict__ P,
                const float4* __restrict__ bg,
                float* __restrict__ o) {
  constexpr int NVT = VV / 64;  // 8 v-tiles
  const int bid = blockIdx.x;
  const int b   = bid / (HH * NVT);
  const int rem = bid % (HH * NVT);
  const int hh  = rem / NVT;
  const int v0  = (rem % NVT) * 64;
  const int tid = threadIdx.x;
  const int lane = tid & 63;
  const int w = tid >> 6;        // 0..7
  const int cw = w & 3;          // col-tile
  const int rw = w >> 2;         // row-group
  const int fr = lane & 15;
  const int kg = lane >> 4;
  const int cc = 16 * cw + fr;   // this thread's output column (c or sigma)
  const int rtA = rw ? 2 : 0;    // first S/U row-tile
  const int rtQ = rw ? 5 : 4;    // Q row-tile (kept in regs)

  __shared__ __align__(16) char smem[SMEM_TOT];
  _Float16* Gp  = (_Float16*)(smem + OSM_G);
  _Float16* WFp = (_Float16*)(smem + OSM_WF);
  float*    WDp = (float*)(smem + OSM_WD);
  _Float16* PMp = (_Float16*)(smem + OSM_PM);
  _Float16* VSp = (_Float16*)(smem + OSM_VS);
  _Float16* HTp = (_Float16*)(smem + OSM_HT);
  _Float16* KTp = (_Float16*)(smem + OSM_KT);
  float*    Up  = (float*)(smem + OSM_U);
  _Float16* UTp = (_Float16*)(smem + OSM_UT);
  float*    SAp = (float*)(smem + OSM_SC);
  float*    SBp = SAp + 64;

  // fp32 state slice: hT[c][k], c = 16rt+kg*4+e (all 64), k = 32w+16ct+fr
  f32x4 hacc[4][2];
#pragma unroll
  for (int i = 0; i < 4; ++i)
#pragma unroll
    for (int j = 0; j < 2; ++j) hacc[i][j] = (f32x4){0.f, 0.f, 0.f, 0.f};
  // zero f16 state copy
  for (int i = tid; i < 33792 / 4; i += 512) ((int*)(smem + OSM_HT))[i] = 0;
  __syncthreads();

#pragma unroll 1
  for (int g = 0; g < TT / 32; ++g) {
    const int t0 = g * 32;
    const int sbase = b * TT + t0;
    const _Float16* Pb = P + (size_t)sbase * PST;

    // ---- Phase A: global -> reg -> LDS, temps die at the barrier ----
    float4 bq;
    {
      f16x8 tmp[6];
#pragma unroll
      for (int i = 0; i < 6; ++i) {
        const int idx = tid + 512 * i;       // 0..3071
        const int r = idx >> 5;
        const int c0 = (idx & 31) << 3;
        const _Float16* src = (r < 64)
            ? Pb + (size_t)(r >> 1) * PST + KOFF + (r & 1) * KEY_DIM + hh * KK + c0
            : Pb + (size_t)(r - 64) * PST + QOFF + hh * KK + c0;
        tmp[i] = *(const f16x8*)src;
      }
      const int mv = tid >> 3, cv = (tid & 7) << 3;
      const f16x8 tv = *(const f16x8*)(Pb + (size_t)(mv >> 1) * PST + VOFF +
                                       (mv & 1) * VAL_DIM + hh * VV + v0 + cv);
      bq = bg[(size_t)(sbase + (lane >> 1)) * HH + hh];
#pragma unroll
      for (int i = 0; i < 6; ++i) {
        const int idx = tid + 512 * i;
        *(f16x8*)&Gp[(idx >> 5) * GP + ((idx & 31) << 3)] = tmp[i];
      }
      *(f16x8*)&VSp[(tid >> 3) * VSP + ((tid & 7) << 3)] = tv;
#pragma unroll
      for (int i = tid; i < 9216 / 4; i += 512) ((int*)(smem + OSM_UT))[i] = 0;
    }
    __syncthreads();

    // ---- Phase B: decay scan (per-wave redundant) + scaled K transpose ----
    float ps = (lane & 1) ? 0.f : bq.w;  // ln(gamma) at even eff-steps
#pragma unroll
    for (int off = 1; off < 64; off <<= 1) {
      float nv = __shfl_up(ps, off);
      if (lane >= off) ps += nv;
    }
    const float tot = __shfl(ps, 63);
    const float Asv = expf(ps);          // A_s (inclusive)
    const float rv2 = expf(tot - ps);    // A63/A_s <= 1
    const float A63r = expf(tot);
    if (w == 0) { SAp[lane] = Asv; SBp[lane] = (lane & 1) ? bq.y : bq.x; }

    // KT[k][s] = (A63/A_s) * Keff[s][k], 4x4 in-reg transpose tiles
    {
      const int ts0 = (tid & 15) * 4;
      const int tk0 = ((tid >> 4) & 31) * 4;
      const float r0 = __shfl(rv2, ts0), r1 = __shfl(rv2, ts0 + 1);
      const float r2 = __shfl(rv2, ts0 + 2), r3 = __shfl(rv2, ts0 + 3);
      const _Float16 rh0 = (_Float16)r0, rh1 = (_Float16)r1;
      const _Float16 rh2 = (_Float16)r2, rh3 = (_Float16)r3;
#pragma unroll
      for (int it = 0; it < 2; ++it) {
        const int k0 = tk0 + 128 * it;
        f16x4 in0 = *(const f16x4*)&Gp[(ts0 + 0) * GP + k0];
        f16x4 in1 = *(const f16x4*)&Gp[(ts0 + 1) * GP + k0];
        f16x4 in2 = *(const f16x4*)&Gp[(ts0 + 2) * GP + k0];
        f16x4 in3 = *(const f16x4*)&Gp[(ts0 + 3) * GP + k0];
#pragma unroll
        for (int j = 0; j < 4; ++j) {
          f16x4 ov;
          ov[0] = in0[j] * rh0; ov[1] = in1[j] * rh1;
          ov[2] = in2[j] * rh2; ov[3] = in3[j] * rh3;
          *(f16x4*)&KTp[(k0 + j) * KTP + ts0] = ov;
        }
      }
    }
    __syncthreads();

    // ---- Phase C: big MFMAs. wave does col-tile cw, row-tiles
    //      {rtA, rtA+1, rtQ}. ph = rows @ hT^T, sq = rows @ Keff^T. ----
    f32x4 ph[3], sq[3];
#pragma unroll
    for (int j = 0; j < 3; ++j) { ph[j] = (f32x4){0.f,0.f,0.f,0.f}; sq[j] = (f32x4){0.f,0.f,0.f,0.f}; }
#pragma unroll
    for (int ks = 0; ks < 8; ++ks) {
      const int ko = ks * 32 + kg * 8;
      const f16x8 bf2 = *(const f16x8*)&HTp[cc * HTP + ko];  // hT col-tile
      const f16x8 bf1 = *(const f16x8*)&Gp[cc * GP + ko];    // Keff col-tile
#pragma unroll
      for (int j = 0; j < 3; ++j) {
        const int rt = (j < 2) ? (rtA + j) : rtQ;
        const f16x8 af = *(const f16x8*)&Gp[(16 * rt + fr) * GP + ko];
        ph[j] = __builtin_amdgcn_mfma_f32_16x16x32_f16(af, bf2, ph[j], 0, 0, 0);
        sq[j] = __builtin_amdgcn_mfma_f32_16x16x32_f16(af, bf1, sq[j], 0, 0, 0);
      }
    }
    // epilogue 1: b -> U (this wave's two row-tiles); Qh0 = ph[2] stays in regs
#pragma unroll
    for (int j = 0; j < 2; ++j) {
      const int rt = rtA + j;
#pragma unroll
      for (int e = 0; e < 4; ++e) {
        const int m = 16 * rt + kg * 4 + e;
        const float vv = (float)VSp[m * VSP + cc];
        Up[m * UP + cc] = SBp[m] * (vv - SAp[m] * ph[j][e]);
      }
    }
    __syncthreads();
    // epilogue 2: W (diag-zeroed f16 + fp32 diag blocks) and Pm, into G overlay
    {
      const float invAsig = 1.f / SAp[cc];
#pragma unroll
      for (int j = 0; j < 2; ++j) {
        const int rt = rtA + j;
#pragma unroll
        for (int e = 0; e < 4; ++e) {
          const int m = 16 * rt + kg * 4 + e;
          const float wv = SBp[m] * (SAp[m] * invAsig) * sq[j][e];
          if ((m >> 4) == cw) {
            WDp[cw * 272 + (m & 15) * 17 + (cc & 15)] = (cc < m) ? wv : 0.f;
            WFp[m * WFP + cc] = (_Float16)0.f;
          } else {
            WFp[m * WFP + cc] = (cc < m) ? (_Float16)wv : (_Float16)0.f;
          }
        }
      }
#pragma unroll
      for (int e = 0; e < 4; ++e) {
        const int tq = 16 * rw + kg * 4 + e;
        const int se = 2 * tq + 1;
        const float pv = (cc <= se) ? (SAp[se] * invAsig) * sq[2][e] : 0.f;
        PMp[tq * PMP + cc] = (_Float16)pv;
      }
    }
    __syncthreads();

    // ---- Phase D: blocked forward substitution (I+W)u = b ----
#pragma unroll 1
    for (int blk = 0; blk < 4; ++blk) {
      if (blk) {
        if (rw == 0) {
          f32x4 ta = (f32x4){0.f, 0.f, 0.f, 0.f};
#pragma unroll
          for (int ks = 0; ks < 2; ++ks) {
            const int ko = ks * 32 + kg * 8;
            const f16x8 af = *(const f16x8*)&WFp[(16 * blk + fr) * WFP + ko];
            const f16x8 bf = *(const f16x8*)&UTp[cc * UTP + ko];
            ta = __builtin_amdgcn_mfma_f32_16x16x32_f16(af, bf, ta, 0, 0, 0);
          }
#pragma unroll
          for (int e = 0; e < 4; ++e) {
            const int m = 16 * blk + kg * 4 + e;
            Up[m * UP + cc] -= ta[e];
          }
        }
        __syncthreads();
      }
      if (w == 0) {  // in-block 16x16 serial solve, lane = column (64 cols)
        float ub[16];
#pragma unroll
        for (int i = 0; i < 16; ++i) ub[i] = Up[(16 * blk + i) * UP + lane];
#pragma unroll
        for (int i = 1; i < 16; ++i)
#pragma unroll
          for (int j = 0; j < i; ++j)
            ub[i] -= WDp[blk * 272 + i * 17 + j] * ub[j];
#pragma unroll
        for (int i = 0; i < 16; ++i) Up[(16 * blk + i) * UP + lane] = ub[i];
        f16x8 p0, p1;
#pragma unroll
        for (int i = 0; i < 8; ++i) { p0[i] = (_Float16)ub[i]; p1[i] = (_Float16)ub[8 + i]; }
        *(f16x8*)&UTp[lane * UTP + 16 * blk]     = p0;
        *(f16x8*)&UTp[lane * UTP + 16 * blk + 8] = p1;
      }
      __syncthreads();
    }

    // ---- Phase E: outputs o = A*Qh0 + Pm @ U (rows 16rw..16rw+15) ----
    {
      f32x4 oa = (f32x4){0.f, 0.f, 0.f, 0.f};
#pragma unroll
      for (int ks = 0; ks < 2; ++ks) {
        const int ko = ks * 32 + kg * 8;
        const f16x8 bf = *(const f16x8*)&UTp[cc * UTP + ko];
        const f16x8 af = *(const f16x8*)&PMp[(16 * rw + fr) * PMP + ko];
        oa = __builtin_amdgcn_mfma_f32_16x16x32_f16(af, bf, oa, 0, 0, 0);
      }
      float* ob = o + ((size_t)sbase * HH + hh) * VV + v0 + cc;
#pragma unroll
      for (int e = 0; e < 4; ++e) {
        const int tq = 16 * rw + kg * 4 + e;
        ob[(size_t)tq * (HH * VV)] = oa[e] + SAp[2 * tq + 1] * ph[2][e];
      }
    }

    // ---- Phase F: state update h = A63*h + KT^T @ U (k-slice 32w..32w+31) ----
#pragma unroll
    for (int rt = 0; rt < 4; ++rt)
#pragma unroll
      for (int ct = 0; ct < 2; ++ct) hacc[rt][ct] *= A63r;
#pragma unroll
    for (int ks = 0; ks < 2; ++ks) {
      const int ko = ks * 32 + kg * 8;
      f16x8 af[4], bf[2];
#pragma unroll
      for (int rt = 0; rt < 4; ++rt) af[rt] = *(const f16x8*)&UTp[(16 * rt + fr) * UTP + ko];
#pragma unroll
      for (int ct = 0; ct < 2; ++ct) bf[ct] = *(const f16x8*)&KTp[(32 * w + 16 * ct + fr) * KTP + ko];
#pragma unroll
      for (int rt = 0; rt < 4; ++rt)
#pragma unroll
        for (int ct = 0; ct < 2; ++ct)
          hacc[rt][ct] = __builtin_amdgcn_mfma_f32_16x16x32_f16(af[rt], bf[ct], hacc[rt][ct], 0, 0, 0);
    }

    // ---- Phase G: refresh f16 state copy ----
#pragma unroll
    for (int rt = 0; rt < 4; ++rt)
#pragma unroll
      for (int ct = 0; ct < 2; ++ct)
#pragma unroll
        for (int e = 0; e < 4; ++e) {
          const int c = 16 * rt + kg * 4 + e;
          const int k = 32 * w + 16 * ct + fr;
          HTp[c * HTP + k] = (_Float16)hacc[rt][ct][e];
        }
    __syncthreads();
  }
}

// ---------------------------------------------------------------------------
// Gated RMSNorm. Reads o_mid fp32 + gate f16 (from P); writes o2 f16.
// ---------------------------------------------------------------------------
__global__ __launch_bounds__(256) void rms_gate_kernel(const float* __restrict__ o,
                                                       const _Float16* __restrict__ P,
                                                       const float* __restrict__ wn,
                                                       short* __restrict__ o2) {
  const int row = blockIdx.x;            // m*H + h
  const int m = row / HH;
  const int hh = row - m * HH;
  const int tid = threadIdx.x;
  const float* op = o + (size_t)row * VV;
  const _Float16* gp = P + (size_t)m * PST + GOFF + hh * VV;
  float a0 = op[tid], a1 = op[tid + 256];
  float ss = a0 * a0 + a1 * a1;
#pragma unroll
  for (int off = 32; off; off >>= 1) ss += __shfl_xor(ss, off);
  __shared__ float red[4];
  const int lane = tid & 63, wv = tid >> 6;
  if (lane == 0) red[wv] = ss;
  __syncthreads();
  float tot = red[0] + red[1] + red[2] + red[3];
  float inv = rsqrt_nr(tot * (1.f / (float)VV) + 1e-5f);
  float r0 = a0 * inv * wn[tid] * sigmoidf_((float)gp[tid]);
  float r1 = a1 * inv * wn[tid + 256] * sigmoidf_((float)gp[tid + 256]);
  _Float16* dst = (_Float16*)o2 + (size_t)m * VAL_DIM + hh * VV;
  dst[tid] = (_Float16)r0;
  dst[tid + 256] = (_Float16)r1;
}

// ---------------------------------------------------------------------------
extern "C" void kernel_launch(void* const* d_in, const int* in_sizes, int n_in,
                              void* d_out, int out_size, void* d_ws, size_t ws_size,
                              hipStream_t stream) {
  (void)in_sizes; (void)n_in; (void)out_size; (void)ws_size;
  const float* x       = (const float*)d_in[0];
  const float* Wq      = (const float*)d_in[1];
  const float* Wk      = (const float*)d_in[2];
  const float* Wv      = (const float*)d_in[3];
  const float* Wb      = (const float*)d_in[4];
  const float* Wa      = (const float*)d_in[5];
  const float* A_log   = (const float*)d_in[6];
  const float* dt_bias = (const float*)d_in[7];
  const float* Wg      = (const float*)d_in[8];
  const float* Wo      = (const float*)d_in[9];
  const float* onw     = (const float*)d_in[10];
  float* out = (float*)d_out;
  float* ws = (float*)d_ws;

  _Float16* P   = (_Float16*)(ws + OFF_P);
  short* wcat   = (short*)(ws + OFF_WCAT);
  short* x16    = (short*)(ws + OFF_X16);
  float* bgw    = ws + OFF_BG;
  float* o_mid  = ws + OFF_OMID;          // overlays Wcat after proj GEMM
  short* o2     = (short*)(ws + OFF_O2);
  short* wo16   = (short*)(ws + OFF_WO16);

  // 1. conversions: x + all projection weights into one concatenated buffer
  cvt_f16<<<4096, 256, 0, stream>>>(x, x16, MM * DD);
  small_proj<<<MM, 256, 0, stream>>>(x, Wb, Wa, A_log, dt_bias, bgw);
  cvt_f16<<<3072, 256, 0, stream>>>(Wq, wcat + (size_t)QOFF * DD, KEY_DIM * DD);
  cvt_f16<<<6144, 256, 0, stream>>>(Wk, wcat + (size_t)KOFF * DD, KEY_DIM * NHOUSE * DD);
  cvt_f16<<<12288, 256, 0, stream>>>(Wv, wcat + (size_t)VOFF * DD, VAL_DIM * NHOUSE * DD);
  cvt_f16<<<6144, 256, 0, stream>>>(Wg, wcat + (size_t)GOFF * DD, VAL_DIM * DD);

  // 2. ONE merged projection GEMM (f16 out, per-column activation), then
  //    in-place k normalization.
  gemm_f16<<<dim3(MM / 128, PST / 128), 256, 0, stream>>>(
      x16, wcat, (void*)P, PST, DD, DD, DD, 4);
  prep_kn<<<MM * NHOUSE * HH / 4, 256, 0, stream>>>(P);

  // 3. chunked MFMA recurrence (f16 operands, fp32 state), 8 waves/block
  recurrence<<<BB * HH * (VV / 64), 512, 0, stream>>>(P, (const float4*)bgw, o_mid);

  // 4. gated RMSNorm -> o2 f16 ; Wo -> f16
  rms_gate_kernel<<<MM * HH, 256, 0, stream>>>(o_mid, P, onw, o2);
  cvt_f16<<<6144, 256, 0, stream>>>(Wo, wo16, DD * VAL_DIM);

  // 5. output GEMM (f16 in, f32 out to d_out)
  gemm_f16<<<dim3(MM / 128, DD / 128), 256, 0, stream>>>(
      o2, wo16, out, DD, VAL_DIM, VAL_DIM, VAL_DIM, 0);
}

// Round 8
// 709.911 us; speedup vs baseline: 1.2403x; 1.0921x over previous
//
#include <hip/hip_runtime.h>
#include <hip/hip_bf16.h>
#include <math.h>

// Problem constants (pinned by reference)
constexpr int BB = 4;
constexpr int TT = 512;
constexpr int DD = 2048;
constexpr int HH = 6;
constexpr int KK = 256;   // head_k_dim
constexpr int VV = 512;   // head_v_dim
constexpr int NHOUSE = 2;
constexpr int MM = BB * TT;          // 2048 rows
constexpr int KEY_DIM = HH * KK;     // 1536
constexpr int VAL_DIM = HH * VV;     // 3072

// P (f16) row layout: q[0,1536) k[1536,4608) v[4608,10752) g[10752,13824)
constexpr int PST  = 13824;
constexpr int QOFF = 0;
constexpr int KOFF = 1536;
constexpr int VOFF = 4608;
constexpr int GOFF = 10752;

// ---- workspace layout (FLOAT units) ----
constexpr size_t SZ_P    = (size_t)MM * PST / 2;         // 14,155,776 (f16)
constexpr size_t SZ_WCAT = (size_t)PST * DD / 2;         // 14,155,776 (f16)
constexpr size_t SZ_X16  = (size_t)MM * DD / 2;          //  2,097,152 (f16)
constexpr size_t SZ_BG   = (size_t)(MM + 2) * HH * 4;    //     49,200
constexpr size_t SZ_OMID = (size_t)MM * VAL_DIM;         //  6,291,456
constexpr size_t SZ_O2   = (size_t)MM * VAL_DIM / 2;     //  1,572,864 (f16)
constexpr size_t SZ_WO16 = (size_t)DD * VAL_DIM / 2;     //  1,572,864 (f16)

constexpr size_t OFF_P    = 0;
constexpr size_t OFF_WCAT = OFF_P + SZ_P;
constexpr size_t OFF_X16  = OFF_WCAT + SZ_WCAT;
constexpr size_t OFF_BG   = OFF_X16 + SZ_X16;
constexpr size_t WS_PEAK  = OFF_BG + SZ_BG;              // 121.8 MB
static_assert(WS_PEAK <= 31494144, "stay under round-4-proven 126.0 MB");
// after proj GEMM: Wcat/x16 dead -> o_mid overlays Wcat
constexpr size_t OFF_OMID = OFF_WCAT;
// after recurrence: o2 + wo16 also inside the (larger) Wcat region
constexpr size_t OFF_O2   = OFF_WCAT + SZ_OMID;
constexpr size_t OFF_WO16 = OFF_O2 + SZ_O2;
static_assert(OFF_WO16 + SZ_WO16 <= OFF_WCAT + SZ_WCAT, "o_mid+o2+wo16 fit in Wcat");

__device__ __forceinline__ float rsqrt_nr(float x) {
  float r = rsqrtf(x);
  return r * (1.5f - 0.5f * x * r * r);
}
__device__ __forceinline__ float sigmoidf_(float x) {
  return 1.f / (1.f + expf(-x));
}
__device__ __forceinline__ short f2h(float f) {
  _Float16 h = (_Float16)f;
  short s;
  __builtin_memcpy(&s, &h, 2);
  return s;
}

typedef __attribute__((ext_vector_type(8))) _Float16 f16x8;
typedef __attribute__((ext_vector_type(4))) _Float16 f16x4;
typedef __attribute__((ext_vector_type(4))) float f32x4;

__device__ __forceinline__ void gload_lds16(const short* g, short* l) {
  __builtin_amdgcn_global_load_lds(
      (const __attribute__((address_space(1))) void*)g,
      (__attribute__((address_space(3))) void*)l, 16, 0, 0);
}

// ---------------------------------------------------------------------------
// fp32 -> fp16 flat conversion, 4 elems/thread.
// ---------------------------------------------------------------------------
__global__ __launch_bounds__(256) void cvt_f16(const float* __restrict__ src,
                                               short* __restrict__ dst, int n) {
  int i = (blockIdx.x * 256 + threadIdx.x) << 2;
  if (i >= n) return;
  float4 v = *(const float4*)(src + i);
  short4 r;
  r.x = f2h(v.x); r.y = f2h(v.y); r.z = f2h(v.z); r.w = f2h(v.w);
  *(short4*)(dst + i) = r;
}

// ---------------------------------------------------------------------------
// C = act(A * B^T). modes: 0 = f32 out, 4 = merged f16 out with per-column
// activation. m97-verified structure.
// ---------------------------------------------------------------------------
__global__ __launch_bounds__(256) void gemm_f16(const short* __restrict__ A,
                                                const short* __restrict__ B,
                                                void* __restrict__ Cout,
                                                int ldc, int Kd, int lda, int ldb,
                                                int mode) {
  __shared__ __align__(16) short lds[8192];
  const int tid = threadIdx.x;
  const int lane = tid & 63;
  const int w = tid >> 6;
  const int m0 = blockIdx.x * 128;
  const int n0 = blockIdx.y * 128;

  const int sr = w * 32 + (lane >> 2);
  const int sc = (lane & 3) << 3;
  const short* ga1 = A + (size_t)(m0 + sr) * lda + sc;
  const short* ga2 = ga1 + (size_t)16 * lda;
  const short* gb1 = B + (size_t)(n0 + sr) * ldb + sc;
  const short* gb2 = gb1 + (size_t)16 * ldb;
  short* la1 = &lds[(size_t)w * 1024];
  short* la2 = la1 + 512;
  short* lb1 = &lds[4096 + (size_t)w * 1024];
  short* lb2 = lb1 + 512;

  const int fr = lane & 15;
  const int kg = lane >> 4;
  const int wmB = (w & 1) * 64;
  const int wnB = (w >> 1) * 64;
  int aoff[4], boff[4];
#pragma unroll
  for (int i = 0; i < 4; ++i) {
    aoff[i] = (wmB + i * 16 + fr) * 32 + kg * 8;
    boff[i] = 4096 + (wnB + i * 16 + fr) * 32 + kg * 8;
  }

  f32x4 acc[4][4];
#pragma unroll
  for (int i = 0; i < 4; ++i)
#pragma unroll
    for (int j = 0; j < 4; ++j) acc[i][j] = (f32x4){0.f, 0.f, 0.f, 0.f};

  const int nk = Kd >> 5;
  for (int kt = 0; kt < nk; ++kt) {
    const int ko = kt << 5;
    __syncthreads();
    gload_lds16(ga1 + ko, la1);
    gload_lds16(ga2 + ko, la2);
    gload_lds16(gb1 + ko, lb1);
    gload_lds16(gb2 + ko, lb2);
    __syncthreads();
    f16x8 af[4], bf[4];
#pragma unroll
    for (int i = 0; i < 4; ++i) af[i] = *(const f16x8*)(lds + aoff[i]);
#pragma unroll
    for (int j = 0; j < 4; ++j) bf[j] = *(const f16x8*)(lds + boff[j]);
#pragma unroll
    for (int i = 0; i < 4; ++i)
#pragma unroll
      for (int j = 0; j < 4; ++j)
        acc[i][j] = __builtin_amdgcn_mfma_f32_16x16x32_f16(af[i], bf[j], acc[i][j], 0, 0, 0);
  }

#pragma unroll
  for (int i = 0; i < 4; ++i) {
    const int row = m0 + wmB + i * 16 + kg * 4;
#pragma unroll
    for (int j = 0; j < 4; ++j) {
      const int col = n0 + wnB + j * 16 + fr;
#pragma unroll
      for (int e = 0; e < 4; ++e) {
        float v = acc[i][j][e];
        if (mode == 4) {
          if (col < GOFF) v = v / (1.f + expf(-v));  // silu (q/k/v)
          if (col < KOFF) v *= 0.0625f;              // q: K^-0.5 folded
          ((_Float16*)Cout)[(size_t)(row + e) * ldc + col] = (_Float16)v;
        } else {
          ((float*)Cout)[(size_t)(row + e) * ldc + col] = v;
        }
      }
    }
  }
}

// ---------------------------------------------------------------------------
// In-place L2-normalization of each f16 k head-row (256 halves) in P.
// ---------------------------------------------------------------------------
__global__ __launch_bounds__(256) void prep_kn(_Float16* __restrict__ P) {
  const int row = blockIdx.x * 4 + (threadIdx.x >> 6);
  const int lane = threadIdx.x & 63;
  const int m = row / (NHOUSE * HH);
  const int rem = row % (NHOUSE * HH);
  const int j = rem / HH;
  const int hh = rem % HH;
  _Float16* p = P + (size_t)m * PST + KOFF + j * KEY_DIM + hh * KK + lane * 4;
  f16x4 v = *(f16x4*)p;
  float f0 = (float)v[0], f1 = (float)v[1], f2 = (float)v[2], f3 = (float)v[3];
  float ss = f0 * f0 + f1 * f1 + f2 * f2 + f3 * f3;
#pragma unroll
  for (int off = 32; off; off >>= 1) ss += __shfl_xor(ss, off);
  float inv = rsqrt_nr(fmaxf(ss, 1e-24f));
  v[0] = (_Float16)(f0 * inv); v[1] = (_Float16)(f1 * inv);
  v[2] = (_Float16)(f2 * inv); v[3] = (_Float16)(f3 * inv);
  *(f16x4*)p = v;
}

// ---------------------------------------------------------------------------
// Small projections: packed float4 per (m,h): {beta0, beta1, exp(g), g}.
// ---------------------------------------------------------------------------
__global__ __launch_bounds__(256) void small_proj(const float* __restrict__ x,
                                                  const float* __restrict__ Wb,
                                                  const float* __restrict__ Wa,
                                                  const float* __restrict__ A_log,
                                                  const float* __restrict__ dt_bias,
                                                  float* __restrict__ bg) {
  const int m = blockIdx.x;
  const int tid = threadIdx.x;
  const int lane = tid & 63;
  const int wv = tid >> 6;
  __shared__ float xs[DD];
  __shared__ float ybuf[18];
#pragma unroll
  for (int i = 0; i < DD / 256; ++i) xs[tid + 256 * i] = x[(size_t)m * DD + tid + 256 * i];
  __syncthreads();
  for (int n = wv; n < 18; n += 4) {
    const float* wrow = (n < 12) ? (Wb + (size_t)n * DD) : (Wa + (size_t)(n - 12) * DD);
    float p = 0.f;
#pragma unroll
    for (int i = 0; i < DD / 64; ++i) p = fmaf(xs[lane + 64 * i], wrow[lane + 64 * i], p);
#pragma unroll
    for (int off = 32; off; off >>= 1) p += __shfl_xor(p, off);
    if (lane == 0) ybuf[n] = p;
  }
  __syncthreads();
  if (tid < 12) {
    const int j = tid / HH, hh = tid % HH;
    bg[((size_t)m * HH + hh) * 4 + j] = 2.f * sigmoidf_(ybuf[tid]);
  } else if (tid < 18) {
    const int hh = tid - 12;
    float z = ybuf[tid] + dt_bias[hh];
    float sp = fmaxf(z, 0.f) + log1pf(expf(-fabsf(z)));
    float g = -expf(A_log[hh]) * sp;
    bg[((size_t)m * HH + hh) * 4 + 2] = expf(g);
    bg[((size_t)m * HH + hh) * 4 + 3] = g;
  }
}

// ---------------------------------------------------------------------------
// Chunked gated delta-rule recurrence on MFMA (WY representation), v2.4:
// identical math to v2.3 (round-7, refcheck-verified). Three diffs:
//  1) XCD co-location: bid = vt*24 + (b*HH+hh). The 8 v-tile blocks of one
//     (b,hh) now sit at bid stride 24 === 0 (mod 8 XCDs) -> same XCD ->
//     7/8 of the shared K/Q staging reads become L2 hits (round-7 FETCH
//     153 MB showed 8x cross-XCD duplication; latency 900 -> ~200 cyc on
//     the serial chunk path).
//  2) staging split into 2 passes of tmp[3] (was tmp[6]): Phase-A live set
//     -24 VGPR -> fits the allocator's hard 128 cap (rounds 4-6: attributes
//     can't move it) -> last ~21 MB/dispatch of scratch spill gone.
//  3) UT zeroing hoisted out of the chunk loop (only chunk 0 needs it:
//     afterwards W's structural zeros multiply stale-but-finite f16; at
//     kernel start LDS could be NaN-patterned, so zero once).
// ---------------------------------------------------------------------------
constexpr int GP  = 264;  // G pitch (halves): [96][264]
constexpr int HTP = 264;  // hT pitch: [64][264]
constexpr int KTP = 72;   // KT pitch: [256][72]
constexpr int UP  = 68;   // U pitch (floats): [64][68]
constexpr int UTP = 72;   // UT pitch (halves): [64][72]
constexpr int WFP = 72;   // Wf16 pitch: [64][72]
constexpr int PMP = 72;   // Pm pitch: [32][72]
constexpr int VSP = 72;   // V-stage pitch: [64][72]
// byte offsets into smem
constexpr int OSM_G  = 0;       // 96*264*2 = 50688 (overlay region below)
constexpr int OSM_WF = 0;       //   64*72*2 = 9216
constexpr int OSM_WD = 9216;    //   4*16*17*4 = 4352
constexpr int OSM_PM = 13568;   //   32*72*2 = 4608  (-> 18176 <= 50688)
constexpr int OSM_VS = 50688;   // 64*72*2 = 9216
constexpr int OSM_HT = 59904;   // 64*264*2 = 33792
constexpr int OSM_KT = 93696;   // 256*72*2 = 36864
constexpr int OSM_U  = 130560;  // 64*68*4 = 17408
constexpr int OSM_UT = 147968;  // 64*72*2 = 9216
constexpr int OSM_SC = 157184;  // scalars: A[64], beta[64]
constexpr int SMEM_TOT = 157696;
static_assert(SMEM_TOT <= 163840, "LDS limit");

__global__ __launch_bounds__(512)
void recurrence(const _Float16* __restrict__ P,
                const float4* __restrict__ bg,
                float* __restrict__ o) {
  const int bid = blockIdx.x;
  const int vt  = bid / (BB * HH);   // v-tile 0..7 (stride-24 bids share XCD)
  const int bhh = bid % (BB * HH);
  const int b   = bhh / HH;
  const int hh  = bhh % HH;
  const int v0  = vt * 64;
  const int tid = threadIdx.x;
  const int lane = tid & 63;
  const int w = tid >> 6;        // 0..7
  const int cw = w & 3;          // col-tile
  const int rw = w >> 2;         // row-group
  const int fr = lane & 15;
  const int kg = lane >> 4;
  const int cc = 16 * cw + fr;   // this thread's output column (c or sigma)
  const int rtA = rw ? 2 : 0;    // first S/U row-tile
  const int rtQ = rw ? 5 : 4;    // Q row-tile (kept in regs)

  __shared__ __align__(16) char smem[SMEM_TOT];
  _Float16* Gp  = (_Float16*)(smem + OSM_G);
  _Float16* WFp = (_Float16*)(smem + OSM_WF);
  float*    WDp = (float*)(smem + OSM_WD);
  _Float16* PMp = (_Float16*)(smem + OSM_PM);
  _Float16* VSp = (_Float16*)(smem + OSM_VS);
  _Float16* HTp = (_Float16*)(smem + OSM_HT);
  _Float16* KTp = (_Float16*)(smem + OSM_KT);
  float*    Up  = (float*)(smem + OSM_U);
  _Float16* UTp = (_Float16*)(smem + OSM_UT);
  float*    SAp = (float*)(smem + OSM_SC);
  float*    SBp = SAp + 64;

  // fp32 state slice: hT[c][k], c = 16rt+kg*4+e (all 64), k = 32w+16ct+fr
  f32x4 hacc[4][2];
#pragma unroll
  for (int i = 0; i < 4; ++i)
#pragma unroll
    for (int j = 0; j < 2; ++j) hacc[i][j] = (f32x4){0.f, 0.f, 0.f, 0.f};
  // zero f16 state copy + UT (UT once: later chunks fully rewrite it, and
  // W's structural zeros make stale finite values harmless)
  for (int i = tid; i < 33792 / 4; i += 512) ((int*)(smem + OSM_HT))[i] = 0;
  for (int i = tid; i < 9216 / 4; i += 512) ((int*)(smem + OSM_UT))[i] = 0;
  __syncthreads();

#pragma unroll 1
  for (int g = 0; g < TT / 32; ++g) {
    const int t0 = g * 32;
    const int sbase = b * TT + t0;
    const _Float16* Pb = P + (size_t)sbase * PST;

    // ---- Phase A: global -> reg -> LDS in 2 passes; temps die fast ----
    float4 bq;
    {
      const int mv = tid >> 3, cv = (tid & 7) << 3;
      const f16x8 tv = *(const f16x8*)(Pb + (size_t)(mv >> 1) * PST + VOFF +
                                       (mv & 1) * VAL_DIM + hh * VV + v0 + cv);
      bq = bg[(size_t)(sbase + (lane >> 1)) * HH + hh];
#pragma unroll
      for (int hp = 0; hp < 2; ++hp) {
        f16x8 tmp[3];
#pragma unroll
        for (int i = 0; i < 3; ++i) {
          const int idx = tid + 512 * (3 * hp + i);   // 0..3071
          const int r = idx >> 5;
          const int c0 = (idx & 31) << 3;
          const _Float16* src = (r < 64)
              ? Pb + (size_t)(r >> 1) * PST + KOFF + (r & 1) * KEY_DIM + hh * KK + c0
              : Pb + (size_t)(r - 64) * PST + QOFF + hh * KK + c0;
          tmp[i] = *(const f16x8*)src;
        }
#pragma unroll
        for (int i = 0; i < 3; ++i) {
          const int idx = tid + 512 * (3 * hp + i);
          *(f16x8*)&Gp[(idx >> 5) * GP + ((idx & 31) << 3)] = tmp[i];
        }
      }
      *(f16x8*)&VSp[(tid >> 3) * VSP + ((tid & 7) << 3)] = tv;
    }
    __syncthreads();

    // ---- Phase B: decay scan (per-wave redundant) + scaled K transpose ----
    float ps = (lane & 1) ? 0.f : bq.w;  // ln(gamma) at even eff-steps
#pragma unroll
    for (int off = 1; off < 64; off <<= 1) {
      float nv = __shfl_up(ps, off);
      if (lane >= off) ps += nv;
    }
    const float tot = __shfl(ps, 63);
    const float Asv = expf(ps);          // A_s (inclusive)
    const float rv2 = expf(tot - ps);    // A63/A_s <= 1
    const float A63r = expf(tot);
    if (w == 0) { SAp[lane] = Asv; SBp[lane] = (lane & 1) ? bq.y : bq.x; }

    // KT[k][s] = (A63/A_s) * Keff[s][k], 4x4 in-reg transpose tiles
    {
      const int ts0 = (tid & 15) * 4;
      const int tk0 = ((tid >> 4) & 31) * 4;
      const float r0 = __shfl(rv2, ts0), r1 = __shfl(rv2, ts0 + 1);
      const float r2 = __shfl(rv2, ts0 + 2), r3 = __shfl(rv2, ts0 + 3);
      const _Float16 rh0 = (_Float16)r0, rh1 = (_Float16)r1;
      const _Float16 rh2 = (_Float16)r2, rh3 = (_Float16)r3;
#pragma unroll
      for (int it = 0; it < 2; ++it) {
        const int k0 = tk0 + 128 * it;
        f16x4 in0 = *(const f16x4*)&Gp[(ts0 + 0) * GP + k0];
        f16x4 in1 = *(const f16x4*)&Gp[(ts0 + 1) * GP + k0];
        f16x4 in2 = *(const f16x4*)&Gp[(ts0 + 2) * GP + k0];
        f16x4 in3 = *(const f16x4*)&Gp[(ts0 + 3) * GP + k0];
#pragma unroll
        for (int j = 0; j < 4; ++j) {
          f16x4 ov;
          ov[0] = in0[j] * rh0; ov[1] = in1[j] * rh1;
          ov[2] = in2[j] * rh2; ov[3] = in3[j] * rh3;
          *(f16x4*)&KTp[(k0 + j) * KTP + ts0] = ov;
        }
      }
    }
    __syncthreads();

    // ---- Phase C: big MFMAs. wave does col-tile cw, row-tiles
    //      {rtA, rtA+1, rtQ}. ph = rows @ hT^T, sq = rows @ Keff^T. ----
    f32x4 ph[3], sq[3];
#pragma unroll
    for (int j = 0; j < 3; ++j) { ph[j] = (f32x4){0.f,0.f,0.f,0.f}; sq[j] = (f32x4){0.f,0.f,0.f,0.f}; }
#pragma unroll
    for (int ks = 0; ks < 8; ++ks) {
      const int ko = ks * 32 + kg * 8;
      const f16x8 bf2 = *(const f16x8*)&HTp[cc * HTP + ko];  // hT col-tile
      const f16x8 bf1 = *(const f16x8*)&Gp[cc * GP + ko];    // Keff col-tile
#pragma unroll
      for (int j = 0; j < 3; ++j) {
        const int rt = (j < 2) ? (rtA + j) : rtQ;
        const f16x8 af = *(const f16x8*)&Gp[(16 * rt + fr) * GP + ko];
        ph[j] = __builtin_amdgcn_mfma_f32_16x16x32_f16(af, bf2, ph[j], 0, 0, 0);
        sq[j] = __builtin_amdgcn_mfma_f32_16x16x32_f16(af, bf1, sq[j], 0, 0, 0);
      }
    }
    // epilogue 1: b -> U (this wave's two row-tiles); Qh0 = ph[2] stays in regs
#pragma unroll
    for (int j = 0; j < 2; ++j) {
      const int rt = rtA + j;
#pragma unroll
      for (int e = 0; e < 4; ++e) {
        const int m = 16 * rt + kg * 4 + e;
        const float vv = (float)VSp[m * VSP + cc];
        Up[m * UP + cc] = SBp[m] * (vv - SAp[m] * ph[j][e]);
      }
    }
    __syncthreads();
    // epilogue 2: W (diag-zeroed f16 + fp32 diag blocks) and Pm, into G overlay
    {
      const float invAsig = 1.f / SAp[cc];
#pragma unroll
      for (int j = 0; j < 2; ++j) {
        const int rt = rtA + j;
#pragma unroll
        for (int e = 0; e < 4; ++e) {
          const int m = 16 * rt + kg * 4 + e;
          const float wv = SBp[m] * (SAp[m] * invAsig) * sq[j][e];
          if ((m >> 4) == cw) {
            WDp[cw * 272 + (m & 15) * 17 + (cc & 15)] = (cc < m) ? wv : 0.f;
            WFp[m * WFP + cc] = (_Float16)0.f;
          } else {
            WFp[m * WFP + cc] = (cc < m) ? (_Float16)wv : (_Float16)0.f;
          }
        }
      }
#pragma unroll
      for (int e = 0; e < 4; ++e) {
        const int tq = 16 * rw + kg * 4 + e;
        const int se = 2 * tq + 1;
        const float pv = (cc <= se) ? (SAp[se] * invAsig) * sq[2][e] : 0.f;
        PMp[tq * PMP + cc] = (_Float16)pv;
      }
    }
    __syncthreads();

    // ---- Phase D: blocked forward substitution (I+W)u = b ----
#pragma unroll 1
    for (int blk = 0; blk < 4; ++blk) {
      if (blk) {
        if (rw == 0) {
          f32x4 ta = (f32x4){0.f, 0.f, 0.f, 0.f};
#pragma unroll
          for (int ks = 0; ks < 2; ++ks) {
            const int ko = ks * 32 + kg * 8;
            const f16x8 af = *(const f16x8*)&WFp[(16 * blk + fr) * WFP + ko];
            const f16x8 bf = *(const f16x8*)&UTp[cc * UTP + ko];
            ta = __builtin_amdgcn_mfma_f32_16x16x32_f16(af, bf, ta, 0, 0, 0);
          }
#pragma unroll
          for (int e = 0; e < 4; ++e) {
            const int m = 16 * blk + kg * 4 + e;
            Up[m * UP + cc] -= ta[e];
          }
        }
        __syncthreads();
      }
      if (w == 0) {  // in-block 16x16 serial solve, lane = column (64 cols)
        float ub[16];
#pragma unroll
        for (int i = 0; i < 16; ++i) ub[i] = Up[(16 * blk + i) * UP + lane];
#pragma unroll
        for (int i = 1; i < 16; ++i)
#pragma unroll
          for (int j = 0; j < i; ++j)
            ub[i] -= WDp[blk * 272 + i * 17 + j] * ub[j];
#pragma unroll
        for (int i = 0; i < 16; ++i) Up[(16 * blk + i) * UP + lane] = ub[i];
        f16x8 p0, p1;
#pragma unroll
        for (int i = 0; i < 8; ++i) { p0[i] = (_Float16)ub[i]; p1[i] = (_Float16)ub[8 + i]; }
        *(f16x8*)&UTp[lane * UTP + 16 * blk]     = p0;
        *(f16x8*)&UTp[lane * UTP + 16 * blk + 8] = p1;
      }
      __syncthreads();
    }

    // ---- Phase E: outputs o = A*Qh0 + Pm @ U (rows 16rw..16rw+15) ----
    {
      f32x4 oa = (f32x4){0.f, 0.f, 0.f, 0.f};
#pragma unroll
      for (int ks = 0; ks < 2; ++ks) {
        const int ko = ks * 32 + kg * 8;
        const f16x8 bf = *(const f16x8*)&UTp[cc * UTP + ko];
        const f16x8 af = *(const f16x8*)&PMp[(16 * rw + fr) * PMP + ko];
        oa = __builtin_amdgcn_mfma_f32_16x16x32_f16(af, bf, oa, 0, 0, 0);
      }
      float* ob = o + ((size_t)sbase * HH + hh) * VV + v0 + cc;
#pragma unroll
      for (int e = 0; e < 4; ++e) {
        const int tq = 16 * rw + kg * 4 + e;
        ob[(size_t)tq * (HH * VV)] = oa[e] + SAp[2 * tq + 1] * ph[2][e];
      }
    }

    // ---- Phase F: state update h = A63*h + KT^T @ U (k-slice 32w..32w+31) ----
#pragma unroll
    for (int rt = 0; rt < 4; ++rt)
#pragma unroll
      for (int ct = 0; ct < 2; ++ct) hacc[rt][ct] *= A63r;
#pragma unroll
    for (int ks = 0; ks < 2; ++ks) {
      const int ko = ks * 32 + kg * 8;
      f16x8 af[4], bf[2];
#pragma unroll
      for (int rt = 0; rt < 4; ++rt) af[rt] = *(const f16x8*)&UTp[(16 * rt + fr) * UTP + ko];
#pragma unroll
      for (int ct = 0; ct < 2; ++ct) bf[ct] = *(const f16x8*)&KTp[(32 * w + 16 * ct + fr) * KTP + ko];
#pragma unroll
      for (int rt = 0; rt < 4; ++rt)
#pragma unroll
        for (int ct = 0; ct < 2; ++ct)
          hacc[rt][ct] = __builtin_amdgcn_mfma_f32_16x16x32_f16(af[rt], bf[ct], hacc[rt][ct], 0, 0, 0);
    }

    // ---- Phase G: refresh f16 state copy ----
#pragma unroll
    for (int rt = 0; rt < 4; ++rt)
#pragma unroll
      for (int ct = 0; ct < 2; ++ct)
#pragma unroll
        for (int e = 0; e < 4; ++e) {
          const int c = 16 * rt + kg * 4 + e;
          const int k = 32 * w + 16 * ct + fr;
          HTp[c * HTP + k] = (_Float16)hacc[rt][ct][e];
        }
    __syncthreads();
  }
}

// ---------------------------------------------------------------------------
// Gated RMSNorm. Reads o_mid fp32 + gate f16 (from P); writes o2 f16.
// ---------------------------------------------------------------------------
__global__ __launch_bounds__(256) void rms_gate_kernel(const float* __restrict__ o,
                                                       const _Float16* __restrict__ P,
                                                       const float* __restrict__ wn,
                                                       short* __restrict__ o2) {
  const int row = blockIdx.x;            // m*H + h
  const int m = row / HH;
  const int hh = row - m * HH;
  const int tid = threadIdx.x;
  const float* op = o + (size_t)row * VV;
  const _Float16* gp = P + (size_t)m * PST + GOFF + hh * VV;
  float a0 = op[tid], a1 = op[tid + 256];
  float ss = a0 * a0 + a1 * a1;
#pragma unroll
  for (int off = 32; off; off >>= 1) ss += __shfl_xor(ss, off);
  __shared__ float red[4];
  const int lane = tid & 63, wv = tid >> 6;
  if (lane == 0) red[wv] = ss;
  __syncthreads();
  float tot = red[0] + red[1] + red[2] + red[3];
  float inv = rsqrt_nr(tot * (1.f / (float)VV) + 1e-5f);
  float r0 = a0 * inv * wn[tid] * sigmoidf_((float)gp[tid]);
  float r1 = a1 * inv * wn[tid + 256] * sigmoidf_((float)gp[tid + 256]);
  _Float16* dst = (_Float16*)o2 + (size_t)m * VAL_DIM + hh * VV;
  dst[tid] = (_Float16)r0;
  dst[tid + 256] = (_Float16)r1;
}

// ---------------------------------------------------------------------------
extern "C" void kernel_launch(void* const* d_in, const int* in_sizes, int n_in,
                              void* d_out, int out_size, void* d_ws, size_t ws_size,
                              hipStream_t stream) {
  (void)in_sizes; (void)n_in; (void)out_size; (void)ws_size;
  const float* x       = (const float*)d_in[0];
  const float* Wq      = (const float*)d_in[1];
  const float* Wk      = (const float*)d_in[2];
  const float* Wv      = (const float*)d_in[3];
  const float* Wb      = (const float*)d_in[4];
  const float* Wa      = (const float*)d_in[5];
  const float* A_log   = (const float*)d_in[6];
  const float* dt_bias = (const float*)d_in[7];
  const float* Wg      = (const float*)d_in[8];
  const float* Wo      = (const float*)d_in[9];
  const float* onw     = (const float*)d_in[10];
  float* out = (float*)d_out;
  float* ws = (float*)d_ws;

  _Float16* P   = (_Float16*)(ws + OFF_P);
  short* wcat   = (short*)(ws + OFF_WCAT);
  short* x16    = (short*)(ws + OFF_X16);
  float* bgw    = ws + OFF_BG;
  float* o_mid  = ws + OFF_OMID;          // overlays Wcat after proj GEMM
  short* o2     = (short*)(ws + OFF_O2);
  short* wo16   = (short*)(ws + OFF_WO16);

  // 1. conversions: x + all projection weights into one concatenated buffer
  cvt_f16<<<4096, 256, 0, stream>>>(x, x16, MM * DD);
  small_proj<<<MM, 256, 0, stream>>>(x, Wb, Wa, A_log, dt_bias, bgw);
  cvt_f16<<<3072, 256, 0, stream>>>(Wq, wcat + (size_t)QOFF * DD, KEY_DIM * DD);
  cvt_f16<<<6144, 256, 0, stream>>>(Wk, wcat + (size_t)KOFF * DD, KEY_DIM * NHOUSE * DD);
  cvt_f16<<<12288, 256, 0, stream>>>(Wv, wcat + (size_t)VOFF * DD, VAL_DIM * NHOUSE * DD);
  cvt_f16<<<6144, 256, 0, stream>>>(Wg, wcat + (size_t)GOFF * DD, VAL_DIM * DD);

  // 2. ONE merged projection GEMM (f16 out, per-column activation), then
  //    in-place k normalization.
  gemm_f16<<<dim3(MM / 128, PST / 128), 256, 0, stream>>>(
      x16, wcat, (void*)P, PST, DD, DD, DD, 4);
  prep_kn<<<MM * NHOUSE * HH / 4, 256, 0, stream>>>(P);

  // 3. chunked MFMA recurrence (f16 operands, fp32 state), 8 waves/block
  recurrence<<<BB * HH * (VV / 64), 512, 0, stream>>>(P, (const float4*)bgw, o_mid);

  // 4. gated RMSNorm -> o2 f16 ; Wo -> f16
  rms_gate_kernel<<<MM * HH, 256, 0, stream>>>(o_mid, P, onw, o2);
  cvt_f16<<<6144, 256, 0, stream>>>(Wo, wo16, DD * VAL_DIM);

  // 5. output GEMM (f16 in, f32 out to d_out)
  gemm_f16<<<dim3(MM / 128, DD / 128), 256, 0, stream>>>(
      o2, wo16, out, DD, VAL_DIM, VAL_DIM, VAL_DIM, 0);
}